// Round 1
// baseline (203.369 us; speedup 1.0000x reference)
//
#include <hip/hip_runtime.h>
#include <hip/hip_bf16.h>

#define N 1024
#define D 64

typedef __attribute__((ext_vector_type(8))) short bf16x8;
typedef __attribute__((ext_vector_type(4))) float f32x4;

__device__ __forceinline__ short f2bf(float x) {
    __hip_bfloat16 b = __float2bfloat16(x);
    return __builtin_bit_cast(short, b);
}

// ---------------------------------------------------------------------------
// Kernel A: hi = X@w1a^T ; hjb = X@w1b^T + b1 ; trf = X@sig_w^T + sig_b ; out = X
// grid (1024, 3), block 64
// ---------------------------------------------------------------------------
__global__ __launch_bounds__(64) void precompute_kernel(
    const float* __restrict__ cell, const float* __restrict__ w1,
    const float* __restrict__ b1, const float* __restrict__ sw,
    const float* __restrict__ sb, float* __restrict__ hi,
    float* __restrict__ hjb, float* __restrict__ trf,
    float* __restrict__ out)
{
    __shared__ float xs[D];
    const int i = blockIdx.x;
    const int t = threadIdx.x;
    xs[t] = cell[(size_t)i * D + t];
    __syncthreads();
    float acc = 0.0f;
    if (blockIdx.y == 0) {
        #pragma unroll 8
        for (int d = 0; d < D; d++) acc += xs[d] * w1[t * 128 + d];
        hi[(size_t)i * D + t] = acc;
    } else if (blockIdx.y == 1) {
        #pragma unroll 8
        for (int d = 0; d < D; d++) acc += xs[d] * w1[t * 128 + 64 + d];
        hjb[(size_t)i * D + t] = acc + b1[t];
    } else {
        #pragma unroll 8
        for (int d = 0; d < D; d++) acc += xs[d] * sw[t * 64 + d];
        trf[(size_t)i * D + t] = acc + sb[t];
        out[(size_t)i * D + t] = xs[t];
    }
}

// ---------------------------------------------------------------------------
// Kernel B: softmax stats per row of sym = 0.5*(A+A^T), diag = 0.
// m_ws[i] = row max ; rs_ws[i] = 1/sum(exp(sym - m))
// grid 1024, block 256
// ---------------------------------------------------------------------------
__global__ __launch_bounds__(256) void softmax_stats_kernel(
    const float* __restrict__ A, float* __restrict__ m_ws,
    float* __restrict__ rs_ws)
{
    const int i = blockIdx.x;
    const int t = threadIdx.x;
    float v[4];
    #pragma unroll
    for (int c = 0; c < 4; c++) {
        int j = t + c * 256;
        v[c] = (j == i) ? 0.0f
                        : 0.5f * (A[(size_t)i * N + j] + A[(size_t)j * N + i]);
    }
    float mx = fmaxf(fmaxf(v[0], v[1]), fmaxf(v[2], v[3]));
    #pragma unroll
    for (int off = 1; off < 64; off <<= 1) mx = fmaxf(mx, __shfl_xor(mx, off));
    __shared__ float redm[4], reds[4];
    const int wid = t >> 6;
    if ((t & 63) == 0) redm[wid] = mx;
    __syncthreads();
    mx = fmaxf(fmaxf(redm[0], redm[1]), fmaxf(redm[2], redm[3]));
    float s = __expf(v[0] - mx) + __expf(v[1] - mx) +
              __expf(v[2] - mx) + __expf(v[3] - mx);
    #pragma unroll
    for (int off = 1; off < 64; off <<= 1) s += __shfl_xor(s, off);
    if ((t & 63) == 0) reds[wid] = s;
    __syncthreads();
    if (t == 0) {
        m_ws[i] = mx;
        rs_ws[i] = 1.0f / (reds[0] + reds[1] + reds[2] + reds[3]);
    }
}

// ---------------------------------------------------------------------------
// Kernel C: fused pairwise gate MLP + weighted accumulation.
// One wave per block. Block (bx, by): i in [bx*16, bx*16+16), j in [by*32, +32).
// grid (64, 32), block 64
// ---------------------------------------------------------------------------
__global__ __launch_bounds__(64) void gate_fused_kernel(
    const float* __restrict__ Adj, const float* __restrict__ hi,
    const float* __restrict__ hjb, const float* __restrict__ trf,
    const float* __restrict__ w2, const float* __restrict__ b2,
    const float* __restrict__ w3, const float* __restrict__ b3,
    const float* __restrict__ m_ws, const float* __restrict__ rs_ws,
    float* __restrict__ out)
{
    const int l  = threadIdx.x;      // 0..63
    const int i0 = blockIdx.x * 16;
    const int j0 = blockIdx.y * 32;
    const int g  = l >> 4;           // k-group for MFMA operand layout
    const int c  = l & 15;           // row (A) / col (B) index in fragment

    // hi fragments: A[row=c][k = s*32 + g*8 + e]
    float ha[16];
    {
        const float* p = &hi[(size_t)(i0 + c) * D + g * 8];
        #pragma unroll
        for (int e = 0; e < 8; e++) { ha[e] = p[e]; ha[8 + e] = p[32 + e]; }
    }

    // w2 B-fragments: B[k][n] = w2[n][k]; n = c (tile0), 16+c (tile1)
    bf16x8 wf00, wf01, wf10, wf11;
    {
        const float* p0 = &w2[(size_t)c * D + g * 8];
        const float* p1 = &w2[(size_t)(16 + c) * D + g * 8];
        #pragma unroll
        for (int e = 0; e < 8; e++) {
            wf00[e] = f2bf(p0[e]);      wf01[e] = f2bf(p0[32 + e]);
            wf10[e] = f2bf(p1[e]);      wf11[e] = f2bf(p1[32 + e]);
        }
    }

    const float b2c0 = b2[c], b2c1 = b2[16 + c];
    const float w3c0 = w3[c], w3c1 = w3[16 + c];
    const float b3v  = b3[0];

    // output-accumulation assignment: pair p = g*4 + (l&3), d-chunk = (l>>2)&3
    const int p_mine  = g * 4 + (l & 3);
    const int i_mine  = i0 + p_mine;
    const int dchunk  = (l >> 2) & 3;
    const float m_mine  = m_ws[i_mine];
    const float rs_mine = rs_ws[i_mine];

    float outacc[16];
    #pragma unroll
    for (int dd = 0; dd < 16; dd++) outacc[dd] = 0.0f;

    for (int j = j0; j < j0 + 32; j++) {
        // h1 = relu(hi + hjb) for this j, as two K=32 bf16 A-fragments
        float hb[16];
        {
            const float* p = &hjb[(size_t)j * D + g * 8];
            #pragma unroll
            for (int e = 0; e < 8; e++) { hb[e] = p[e]; hb[8 + e] = p[32 + e]; }
        }
        bf16x8 a0, a1;
        #pragma unroll
        for (int e = 0; e < 8; e++) {
            a0[e] = f2bf(fmaxf(ha[e] + hb[e], 0.0f));
            a1[e] = f2bf(fmaxf(ha[8 + e] + hb[8 + e], 0.0f));
        }

        f32x4 acc0 = {0.0f, 0.0f, 0.0f, 0.0f};
        f32x4 acc1 = {0.0f, 0.0f, 0.0f, 0.0f};
        acc0 = __builtin_amdgcn_mfma_f32_16x16x32_bf16(a0, wf00, acc0, 0, 0, 0);
        acc0 = __builtin_amdgcn_mfma_f32_16x16x32_bf16(a1, wf01, acc0, 0, 0, 0);
        acc1 = __builtin_amdgcn_mfma_f32_16x16x32_bf16(a0, wf10, acc1, 0, 0, 0);
        acc1 = __builtin_amdgcn_mfma_f32_16x16x32_bf16(a1, wf11, acc1, 0, 0, 0);

        // per-lane partial of gate_pre for its 4 pairs (rows g*4+r)
        float tq[4];
        #pragma unroll
        for (int r = 0; r < 4; r++) {
            float h2a = fmaxf(acc0[r] + b2c0, 0.0f);
            float h2b = fmaxf(acc1[r] + b2c1, 0.0f);
            tq[r] = w3c0 * h2a + w3c1 * h2b;
        }
        #pragma unroll
        for (int r = 0; r < 4; r++) {
            #pragma unroll
            for (int m = 1; m < 16; m <<= 1) tq[r] += __shfl_xor(tq[r], m);
        }
        // select tq[l&3] without dynamic indexing
        float ta = (l & 1) ? tq[1] : tq[0];
        float tb = (l & 1) ? tq[3] : tq[2];
        float gp = (l & 2) ? tb : ta;

        float gate = 1.0f / (1.0f + __expf(-(gp + b3v)));
        float sym  = 0.5f * (Adj[(size_t)i_mine * N + j] +
                             Adj[(size_t)j * N + i_mine]);
        float wgt  = (i_mine == j) ? 0.0f
                                   : gate * __expf(sym - m_mine) * rs_mine;

        const float* tp = &trf[(size_t)j * D + dchunk * 16];
        #pragma unroll
        for (int dd = 0; dd < 16; dd++) outacc[dd] += wgt * tp[dd];
    }

    float* op = &out[(size_t)i_mine * D + dchunk * 16];
    #pragma unroll
    for (int dd = 0; dd < 16; dd++) atomicAdd(&op[dd], outacc[dd]);
}

// ---------------------------------------------------------------------------
extern "C" void kernel_launch(void* const* d_in, const int* in_sizes, int n_in,
                              void* d_out, int out_size, void* d_ws, size_t ws_size,
                              hipStream_t stream) {
    const float* cell = (const float*)d_in[0];
    const float* adj  = (const float*)d_in[1];
    const float* w1   = (const float*)d_in[2];
    const float* b1   = (const float*)d_in[3];
    const float* w2   = (const float*)d_in[4];
    const float* b2   = (const float*)d_in[5];
    const float* w3   = (const float*)d_in[6];
    const float* b3   = (const float*)d_in[7];
    const float* sw   = (const float*)d_in[8];
    const float* sb   = (const float*)d_in[9];
    float* out = (float*)d_out;

    float* ws    = (float*)d_ws;
    float* m_ws  = ws;                 // 1024
    float* rs_ws = ws + 1024;          // 1024
    float* hi    = ws + 2048;          // 65536
    float* hjb   = hi + N * D;         // 65536
    float* trf   = hjb + N * D;        // 65536

    precompute_kernel<<<dim3(N, 3), 64, 0, stream>>>(cell, w1, b1, sw, sb,
                                                     hi, hjb, trf, out);
    softmax_stats_kernel<<<N, 256, 0, stream>>>(adj, m_ws, rs_ws);
    gate_fused_kernel<<<dim3(64, 32), 64, 0, stream>>>(adj, hi, hjb, trf,
                                                       w2, b2, w3, b3,
                                                       m_ws, rs_ws, out);
}

// Round 2
// 49.013 us; speedup vs baseline: 4.1493x; 4.1493x over previous
//
#include <hip/hip_runtime.h>
#include <hip/hip_bf16.h>

#define N 1024
#define D 64

typedef __attribute__((ext_vector_type(8))) short bf16x8;
typedef __attribute__((ext_vector_type(16))) float f32x16;

__device__ __forceinline__ short f2bf(float x) {
    __hip_bfloat16 b = __float2bfloat16(x);
    return __builtin_bit_cast(short, b);
}

// ---------------------------------------------------------------------------
// Kernel A: hi = X@w1a^T ; hjb = X@w1b^T + b1 ; trf = X@sig_w^T + sig_b ; out = X
// grid (1024, 3), block 64
// ---------------------------------------------------------------------------
__global__ __launch_bounds__(64) void precompute_kernel(
    const float* __restrict__ cell, const float* __restrict__ w1,
    const float* __restrict__ b1, const float* __restrict__ sw,
    const float* __restrict__ sb, float* __restrict__ hi,
    float* __restrict__ hjb, float* __restrict__ trf,
    float* __restrict__ out)
{
    __shared__ float xs[D];
    const int i = blockIdx.x;
    const int t = threadIdx.x;
    xs[t] = cell[(size_t)i * D + t];
    __syncthreads();
    float acc = 0.0f;
    if (blockIdx.y == 0) {
        #pragma unroll 8
        for (int d = 0; d < D; d++) acc += xs[d] * w1[t * 128 + d];
        hi[(size_t)i * D + t] = acc;
    } else if (blockIdx.y == 1) {
        #pragma unroll 8
        for (int d = 0; d < D; d++) acc += xs[d] * w1[t * 128 + 64 + d];
        hjb[(size_t)i * D + t] = acc + b1[t];
    } else {
        #pragma unroll 8
        for (int d = 0; d < D; d++) acc += xs[d] * sw[t * 64 + d];
        trf[(size_t)i * D + t] = acc + sb[t];
        out[(size_t)i * D + t] = xs[t];
    }
}

// ---------------------------------------------------------------------------
// Kernel B: S = 0.5*(A+A^T), diag 0 (symmetric -> row j serves column j too);
// softmax stats m_ws[i] = row max, rs_ws[i] = 1/sum(exp(S - m)).
// grid 1024, block 256
// ---------------------------------------------------------------------------
__global__ __launch_bounds__(256) void stats_kernel(
    const float* __restrict__ A, float* __restrict__ S,
    float* __restrict__ m_ws, float* __restrict__ rs_ws)
{
    const int i = blockIdx.x;
    const int t = threadIdx.x;
    float v[4];
    #pragma unroll
    for (int c = 0; c < 4; c++) {
        int j = t + c * 256;
        v[c] = (j == i) ? 0.0f
                        : 0.5f * (A[(size_t)i * N + j] + A[(size_t)j * N + i]);
        S[(size_t)i * N + j] = v[c];
    }
    float mx = fmaxf(fmaxf(v[0], v[1]), fmaxf(v[2], v[3]));
    #pragma unroll
    for (int off = 1; off < 64; off <<= 1) mx = fmaxf(mx, __shfl_xor(mx, off));
    __shared__ float redm[4], reds[4];
    const int wid = t >> 6;
    if ((t & 63) == 0) redm[wid] = mx;
    __syncthreads();
    mx = fmaxf(fmaxf(redm[0], redm[1]), fmaxf(redm[2], redm[3]));
    float s = __expf(v[0] - mx) + __expf(v[1] - mx) +
              __expf(v[2] - mx) + __expf(v[3] - mx);
    #pragma unroll
    for (int off = 1; off < 64; off <<= 1) s += __shfl_xor(s, off);
    if ((t & 63) == 0) reds[wid] = s;
    __syncthreads();
    if (t == 0) {
        m_ws[i] = mx;
        rs_ws[i] = 1.0f / (reds[0] + reds[1] + reds[2] + reds[3]);
    }
}

// ---------------------------------------------------------------------------
// Kernel C: fused pairwise gate MLP + weighted accumulation, swapped-operand
// 32x32x16 MFMA: D[ch][pair] = w2 . h1^T  -> gate reduce is in-register.
// Block: 4 waves, i-tile 32 (shared), wave w does j in [by*64+w*16, +16).
// grid (32, 16), block 256.
// ---------------------------------------------------------------------------
__global__ __launch_bounds__(256, 2) void gate_fused_kernel(
    const float* __restrict__ S, const float* __restrict__ hi,
    const float* __restrict__ hjb, const float* __restrict__ trf,
    const float* __restrict__ w2, const float* __restrict__ b2,
    const float* __restrict__ w3, const float* __restrict__ b3,
    const float* __restrict__ m_ws, const float* __restrict__ rs_ws,
    float* __restrict__ out)
{
    __shared__ float red[4 * 2048];
    const int t   = threadIdx.x;
    const int w   = t >> 6;
    const int l   = t & 63;
    const int i0  = blockIdx.x * 32;
    const int jbase = blockIdx.y * 64 + w * 16;
    const int p   = l & 31;          // pair (B col) AND w2 row served by lane
    const int hi8 = l >> 5;          // k-subgroup: k = q*16 + hi8*8 + e
    const int i_mine = i0 + p;

    // hi tile: lane's 32 k-values for its pair
    float hv[32];
    #pragma unroll
    for (int q = 0; q < 4; q++) {
        const float* hp = &hi[(size_t)i_mine * D + q * 16 + hi8 * 8];
        #pragma unroll
        for (int e = 0; e < 8; e++) hv[q * 8 + e] = hp[e];
    }

    // w2 A-frags: A[row=ch=l&31][k]
    bf16x8 wa[4];
    #pragma unroll
    for (int q = 0; q < 4; q++) {
        const float* wp = &w2[(size_t)p * D + q * 16 + hi8 * 8];
        #pragma unroll
        for (int e = 0; e < 8; e++) wa[q][e] = f2bf(wp[e]);
    }

    // per-acc-reg channel constants: ch = (r&3) + 8*(r>>2) + 4*hi8
    float b2r[16], w3r[16];
    #pragma unroll
    for (int r = 0; r < 16; r++) {
        int ch = (r & 3) + 8 * (r >> 2) + 4 * hi8;
        b2r[r] = b2[ch];
        w3r[r] = w3[ch];
    }

    // trf B-frags for the out-MFMA (k = jj = hi8*8+e, col = d)
    bf16x8 tf0, tf1;
    #pragma unroll
    for (int e = 0; e < 8; e++) {
        const float* tp = &trf[(size_t)(jbase + hi8 * 8 + e) * D];
        tf0[e] = f2bf(tp[p]);
        tf1[e] = f2bf(tp[32 + p]);
    }

    const float m_mine  = m_ws[i_mine];
    const float rs_mine = rs_ws[i_mine];
    const float b3v     = b3[0];

    bf16x8 wf = {0, 0, 0, 0, 0, 0, 0, 0};
    f32x16 oA, oB;
    #pragma unroll
    for (int r = 0; r < 16; r++) { oA[r] = 0.0f; oB[r] = 0.0f; }

    #pragma unroll
    for (int jj = 0; jj < 16; jj++) {
        const int j = jbase + jj;
        // B-frags: h1[p][k] = relu(hi + hjb), hjb broadcast across 32 lanes
        const float* hbp = &hjb[(size_t)j * D];
        bf16x8 bq[4];
        #pragma unroll
        for (int q = 0; q < 4; q++) {
            const float* hp = &hbp[q * 16 + hi8 * 8];
            #pragma unroll
            for (int e = 0; e < 8; e++)
                bq[q][e] = f2bf(fmaxf(hv[q * 8 + e] + hp[e], 0.0f));
        }

        f32x16 accA, accB;
        #pragma unroll
        for (int r = 0; r < 16; r++) { accA[r] = b2r[r]; accB[r] = 0.0f; }
        accA = __builtin_amdgcn_mfma_f32_32x32x16_bf16(wa[0], bq[0], accA, 0, 0, 0);
        accA = __builtin_amdgcn_mfma_f32_32x32x16_bf16(wa[1], bq[1], accA, 0, 0, 0);
        accB = __builtin_amdgcn_mfma_f32_32x32x16_bf16(wa[2], bq[2], accB, 0, 0, 0);
        accB = __builtin_amdgcn_mfma_f32_32x32x16_bf16(wa[3], bq[3], accB, 0, 0, 0);

        // gate_pre[p] = sum_ch relu(h2pre + b2) * w3  (b2 folded into accA init)
        float gp = 0.0f;
        #pragma unroll
        for (int r = 0; r < 16; r++)
            gp = fmaf(fmaxf(accA[r] + accB[r], 0.0f), w3r[r], gp);
        gp += __shfl_xor(gp, 32);

        float gate = 1.0f / (1.0f + __expf(-(gp + b3v)));
        float sym  = S[(size_t)j * N + i_mine];   // S symmetric: row j works
        float wgt  = (i_mine == j) ? 0.0f
                                   : gate * __expf(sym - m_mine) * rs_mine;
        short wb = f2bf(wgt);
        wf[jj & 7] = ((jj >> 3) == hi8) ? wb : wf[jj & 7];
    }

    // out tile partial: W(32i x 16j) @ trf(16j x 64d) via two MFMAs
    oA = __builtin_amdgcn_mfma_f32_32x32x16_bf16(wf, tf0, oA, 0, 0, 0);
    oB = __builtin_amdgcn_mfma_f32_32x32x16_bf16(wf, tf1, oB, 0, 0, 0);

    // cross-wave reduce via LDS, then one atomicAdd per element
    #pragma unroll
    for (int r = 0; r < 16; r++) {
        int row = (r & 3) + 8 * (r >> 2) + 4 * hi8;
        red[w * 2048 + row * 64 + p]      = oA[r];
        red[w * 2048 + row * 64 + 32 + p] = oB[r];
    }
    __syncthreads();
    #pragma unroll
    for (int e = 0; e < 8; e++) {
        int idx = t + e * 256;
        float s = red[idx] + red[2048 + idx] + red[4096 + idx] + red[6144 + idx];
        atomicAdd(&out[(size_t)i0 * D + idx], s);
    }
}

// ---------------------------------------------------------------------------
extern "C" void kernel_launch(void* const* d_in, const int* in_sizes, int n_in,
                              void* d_out, int out_size, void* d_ws, size_t ws_size,
                              hipStream_t stream) {
    const float* cell = (const float*)d_in[0];
    const float* adj  = (const float*)d_in[1];
    const float* w1   = (const float*)d_in[2];
    const float* b1   = (const float*)d_in[3];
    const float* w2   = (const float*)d_in[4];
    const float* b2   = (const float*)d_in[5];
    const float* w3   = (const float*)d_in[6];
    const float* b3   = (const float*)d_in[7];
    const float* sw   = (const float*)d_in[8];
    const float* sb   = (const float*)d_in[9];
    float* out = (float*)d_out;

    float* ws    = (float*)d_ws;
    float* m_ws  = ws;                 // 1024
    float* rs_ws = ws + 1024;          // 1024
    float* hi    = ws + 2048;          // 64K
    float* hjb   = hi + N * D;         // 64K
    float* trf   = hjb + N * D;        // 64K
    float* S     = trf + N * D;        // 1M floats (4 MB)

    precompute_kernel<<<dim3(N, 3), 64, 0, stream>>>(cell, w1, b1, sw, sb,
                                                     hi, hjb, trf, out);
    stats_kernel<<<N, 256, 0, stream>>>(adj, S, m_ws, rs_ws);
    gate_fused_kernel<<<dim3(32, 16), 256, 0, stream>>>(S, hi, hjb, trf,
                                                        w2, b2, w3, b3,
                                                        m_ws, rs_ws, out);
}

// Round 3
// 35.704 us; speedup vs baseline: 5.6959x; 1.3727x over previous
//
#include <hip/hip_runtime.h>
#include <hip/hip_bf16.h>

#define N 1024
#define D 64

typedef __attribute__((ext_vector_type(8))) short bf16x8;
typedef __attribute__((ext_vector_type(16))) float f32x16;

__device__ __forceinline__ short f2bf(float x) {
    __hip_bfloat16 b = __float2bfloat16(x);
    return __builtin_bit_cast(short, b);
}

// ---------------------------------------------------------------------------
// K1: S = 0.5*(A+A^T) with zero diag (tiled, coalesced both directions) +
// per-(row, j-tile) softmax partials: maxp[row][bj], sump[row][bj].
// grid (16,16), block 256. Tile 64x64.
// ---------------------------------------------------------------------------
__global__ __launch_bounds__(256) void symS_kernel(
    const float* __restrict__ A, float* __restrict__ S,
    float* __restrict__ maxp, float* __restrict__ sump)
{
    __shared__ float t2[64 * 65];
    const int bi = blockIdx.x, bj = blockIdx.y;
    const int t = threadIdx.x;
    // stage A[bj-tile][bi-tile] (the transposed source), coalesced
    #pragma unroll
    for (int k = 0; k < 4; k++) {
        int f4 = t + 256 * k;
        int r2 = f4 >> 4, c4 = (f4 & 15) * 4;
        float4 v = *(const float4*)&A[(size_t)(bj * 64 + r2) * N + bi * 64 + c4];
        t2[r2 * 65 + c4 + 0] = v.x;
        t2[r2 * 65 + c4 + 1] = v.y;
        t2[r2 * 65 + c4 + 2] = v.z;
        t2[r2 * 65 + c4 + 3] = v.w;
    }
    __syncthreads();
    const int r  = t >> 2;          // local row 0..63 (4 threads per row)
    const int cq = (t & 3) * 16;    // col base
    const int gi = bi * 64 + r;
    float vals[16];
    #pragma unroll
    for (int k = 0; k < 4; k++) {
        float4 a1 = *(const float4*)&A[(size_t)gi * N + bj * 64 + cq + k * 4];
        float tmp[4] = {a1.x, a1.y, a1.z, a1.w};
        #pragma unroll
        for (int e = 0; e < 4; e++) {
            int c = cq + k * 4 + e;
            float sv = 0.5f * (tmp[e] + t2[c * 65 + r]);
            if (bi == bj && r == c) sv = 0.0f;
            vals[k * 4 + e] = sv;
        }
    }
    #pragma unroll
    for (int k = 0; k < 4; k++) {
        float4 sv = {vals[k * 4], vals[k * 4 + 1], vals[k * 4 + 2], vals[k * 4 + 3]};
        *(float4*)&S[(size_t)gi * N + bj * 64 + cq + k * 4] = sv;
    }
    // row-tile partial max / expsum (reduce across the 4 threads of the row)
    float mx = vals[0];
    #pragma unroll
    for (int e = 1; e < 16; e++) mx = fmaxf(mx, vals[e]);
    mx = fmaxf(mx, __shfl_xor(mx, 1));
    mx = fmaxf(mx, __shfl_xor(mx, 2));
    float s = 0.0f;
    #pragma unroll
    for (int e = 0; e < 16; e++) s += __expf(vals[e] - mx);
    s += __shfl_xor(s, 1);
    s += __shfl_xor(s, 2);
    if ((t & 3) == 0) {
        maxp[(size_t)gi * 16 + bj] = mx;
        sump[(size_t)gi * 16 + bj] = s;
    }
}

// ---------------------------------------------------------------------------
// K2: combine tile partials -> m_ws, rs_ws. grid 4, block 256 (thread = row).
// ---------------------------------------------------------------------------
__global__ __launch_bounds__(256) void stats2_kernel(
    const float* __restrict__ maxp, const float* __restrict__ sump,
    float* __restrict__ m_ws, float* __restrict__ rs_ws)
{
    const int row = blockIdx.x * 256 + threadIdx.x;
    float m = -1e30f;
    #pragma unroll
    for (int k = 0; k < 16; k++) m = fmaxf(m, maxp[(size_t)row * 16 + k]);
    float s = 0.0f;
    #pragma unroll
    for (int k = 0; k < 16; k++)
        s += sump[(size_t)row * 16 + k] * __expf(maxp[(size_t)row * 16 + k] - m);
    m_ws[row]  = m;
    rs_ws[row] = 1.0f / s;
}

// ---------------------------------------------------------------------------
// K3: hi = X@w1a^T ; hjb = X@w1b^T + b1 ; trf = X@sig_w^T + sb.
// LDS-staged weights (+1 pad -> conflict-free), i-tile 4, grid 256, block 256.
// ---------------------------------------------------------------------------
__global__ __launch_bounds__(256) void precompute_kernel(
    const float* __restrict__ cell, const float* __restrict__ w1,
    const float* __restrict__ b1, const float* __restrict__ sw,
    const float* __restrict__ sb,
    float* __restrict__ hi, float* __restrict__ hjb, float* __restrict__ trf)
{
    __shared__ float w1s[64 * 129];
    __shared__ float sws[64 * 65];
    __shared__ float xs[4 * 64];
    const int t = threadIdx.x;
    const int b = blockIdx.x;
    #pragma unroll
    for (int k = 0; k < 8; k++) {
        int f4 = t + 256 * k;
        int row = f4 >> 5, c4 = (f4 & 31) * 4;
        float4 v = *(const float4*)&w1[(size_t)row * 128 + c4];
        w1s[row * 129 + c4 + 0] = v.x;
        w1s[row * 129 + c4 + 1] = v.y;
        w1s[row * 129 + c4 + 2] = v.z;
        w1s[row * 129 + c4 + 3] = v.w;
    }
    #pragma unroll
    for (int k = 0; k < 4; k++) {
        int f4 = t + 256 * k;
        int row = f4 >> 4, c4 = (f4 & 15) * 4;
        float4 v = *(const float4*)&sw[(size_t)row * 64 + c4];
        sws[row * 65 + c4 + 0] = v.x;
        sws[row * 65 + c4 + 1] = v.y;
        sws[row * 65 + c4 + 2] = v.z;
        sws[row * 65 + c4 + 3] = v.w;
    }
    xs[t] = cell[(size_t)b * 256 + t];
    __syncthreads();
    const int wv = t >> 6, l = t & 63;
    const float* xr = &xs[wv * 64];
    float a0 = 0.0f, a1 = 0.0f, a2 = 0.0f;
    #pragma unroll 16
    for (int d = 0; d < 64; d++) {
        float x = xr[d];
        a0 = fmaf(x, w1s[l * 129 + d], a0);
        a1 = fmaf(x, w1s[l * 129 + 64 + d], a1);
        a2 = fmaf(x, sws[l * 65 + d], a2);
    }
    const int i = b * 4 + wv;
    hi[(size_t)i * D + l]  = a0;
    hjb[(size_t)i * D + l] = a1 + b1[l];
    trf[(size_t)i * D + l] = a2 + sb[l];
}

// ---------------------------------------------------------------------------
// K4: fused pairwise gate MLP + weighted accumulation (swapped-operand 32x32
// MFMA). Block: 4 waves, i-tile 32, j-tile 64 (16 j per wave). LDS-staged
// hjb + S-slice; LDS cross-wave reduce (aliased); partial write (no atomics).
// grid (32,16), block 256.
// ---------------------------------------------------------------------------
__global__ __launch_bounds__(256, 3) void gate_fused_kernel(
    const float* __restrict__ S, const float* __restrict__ hi,
    const float* __restrict__ hjb, const float* __restrict__ trf,
    const float* __restrict__ w2, const float* __restrict__ b2,
    const float* __restrict__ w3, const float* __restrict__ b3,
    const float* __restrict__ m_ws, const float* __restrict__ rs_ws,
    float* __restrict__ part)
{
    __shared__ float smem[8192];          // hjb_s[4096] | S_s[2048] ; reused as red[8192]
    float* hjb_s = smem;
    float* S_s   = smem + 4096;
    const int t   = threadIdx.x;
    const int w   = t >> 6;
    const int l   = t & 63;
    const int i0  = blockIdx.x * 32;
    const int by  = blockIdx.y;
    const int jb0 = by * 64;
    const int jbase = jb0 + w * 16;
    const int p   = l & 31;
    const int hi8 = l >> 5;
    const int i_mine = i0 + p;

    // stage hjb rows [jb0, jb0+64)
    #pragma unroll
    for (int k = 0; k < 4; k++) {
        int f4 = t + 256 * k;
        float4 v = *(const float4*)&hjb[(size_t)jb0 * D + f4 * 4];
        *(float4*)&hjb_s[f4 * 4] = v;
    }
    // stage S slice [64 j][32 i]
    #pragma unroll
    for (int k = 0; k < 2; k++) {
        int f4 = t + 256 * k;
        int row = f4 >> 3, c4 = (f4 & 7) * 4;
        float4 v = *(const float4*)&S[(size_t)(jb0 + row) * N + i0 + c4];
        *(float4*)&S_s[row * 32 + c4] = v;
    }

    // per-lane loop-invariant operands
    float hv[32];
    #pragma unroll
    for (int q = 0; q < 4; q++) {
        float4 v0 = *(const float4*)&hi[(size_t)i_mine * D + q * 16 + hi8 * 8];
        float4 v1 = *(const float4*)&hi[(size_t)i_mine * D + q * 16 + hi8 * 8 + 4];
        hv[q * 8 + 0] = v0.x; hv[q * 8 + 1] = v0.y;
        hv[q * 8 + 2] = v0.z; hv[q * 8 + 3] = v0.w;
        hv[q * 8 + 4] = v1.x; hv[q * 8 + 5] = v1.y;
        hv[q * 8 + 6] = v1.z; hv[q * 8 + 7] = v1.w;
    }
    bf16x8 wa[4];
    #pragma unroll
    for (int q = 0; q < 4; q++) {
        const float* wp = &w2[(size_t)p * D + q * 16 + hi8 * 8];
        #pragma unroll
        for (int e = 0; e < 8; e++) wa[q][e] = f2bf(wp[e]);
    }
    float b2r[16], w3r[16];
    #pragma unroll
    for (int r = 0; r < 16; r++) {
        int ch = (r & 3) + 8 * (r >> 2) + 4 * hi8;
        b2r[r] = b2[ch];
        w3r[r] = w3[ch];
    }
    const float m_mine  = m_ws[i_mine];
    const float rs_mine = rs_ws[i_mine];
    const float b3v     = b3[0];

    __syncthreads();

    bf16x8 wf = {0, 0, 0, 0, 0, 0, 0, 0};
    #pragma unroll
    for (int jj = 0; jj < 16; jj++) {
        const int j_loc = w * 16 + jj;
        const int j = jb0 + j_loc;
        bf16x8 bq[4];
        #pragma unroll
        for (int q = 0; q < 4; q++) {
            float4 h0 = *(const float4*)&hjb_s[j_loc * 64 + q * 16 + hi8 * 8];
            float4 h1 = *(const float4*)&hjb_s[j_loc * 64 + q * 16 + hi8 * 8 + 4];
            bq[q][0] = f2bf(fmaxf(hv[q * 8 + 0] + h0.x, 0.0f));
            bq[q][1] = f2bf(fmaxf(hv[q * 8 + 1] + h0.y, 0.0f));
            bq[q][2] = f2bf(fmaxf(hv[q * 8 + 2] + h0.z, 0.0f));
            bq[q][3] = f2bf(fmaxf(hv[q * 8 + 3] + h0.w, 0.0f));
            bq[q][4] = f2bf(fmaxf(hv[q * 8 + 4] + h1.x, 0.0f));
            bq[q][5] = f2bf(fmaxf(hv[q * 8 + 5] + h1.y, 0.0f));
            bq[q][6] = f2bf(fmaxf(hv[q * 8 + 6] + h1.z, 0.0f));
            bq[q][7] = f2bf(fmaxf(hv[q * 8 + 7] + h1.w, 0.0f));
        }
        f32x16 accA, accB;
        #pragma unroll
        for (int r = 0; r < 16; r++) { accA[r] = b2r[r]; accB[r] = 0.0f; }
        accA = __builtin_amdgcn_mfma_f32_32x32x16_bf16(wa[0], bq[0], accA, 0, 0, 0);
        accA = __builtin_amdgcn_mfma_f32_32x32x16_bf16(wa[1], bq[1], accA, 0, 0, 0);
        accB = __builtin_amdgcn_mfma_f32_32x32x16_bf16(wa[2], bq[2], accB, 0, 0, 0);
        accB = __builtin_amdgcn_mfma_f32_32x32x16_bf16(wa[3], bq[3], accB, 0, 0, 0);

        float gp = 0.0f;
        #pragma unroll
        for (int r = 0; r < 16; r++)
            gp = fmaf(fmaxf(accA[r] + accB[r], 0.0f), w3r[r], gp);
        gp += __shfl_xor(gp, 32);

        float gate = 1.0f / (1.0f + __expf(-(gp + b3v)));
        float sym  = S_s[j_loc * 32 + p];
        float wgt  = (i_mine == j) ? 0.0f
                                   : gate * __expf(sym - m_mine) * rs_mine;
        short wb = f2bf(wgt);
        wf[jj & 7] = ((jj >> 3) == hi8) ? wb : wf[jj & 7];
    }

    // post-loop: trf B-frags (k = local j), out tile = W @ trf
    bf16x8 tf0, tf1;
    #pragma unroll
    for (int e = 0; e < 8; e++) {
        const float* tp = &trf[(size_t)(jbase + hi8 * 8 + e) * D];
        tf0[e] = f2bf(tp[p]);
        tf1[e] = f2bf(tp[32 + p]);
    }
    f32x16 oA, oB;
    #pragma unroll
    for (int r = 0; r < 16; r++) { oA[r] = 0.0f; oB[r] = 0.0f; }
    oA = __builtin_amdgcn_mfma_f32_32x32x16_bf16(wf, tf0, oA, 0, 0, 0);
    oB = __builtin_amdgcn_mfma_f32_32x32x16_bf16(wf, tf1, oB, 0, 0, 0);

    __syncthreads();   // all waves done reading staged LDS
    float* red = smem;
    #pragma unroll
    for (int r = 0; r < 16; r++) {
        int row = (r & 3) + 8 * (r >> 2) + 4 * hi8;
        red[w * 2048 + row * 64 + p]      = oA[r];
        red[w * 2048 + row * 64 + 32 + p] = oB[r];
    }
    __syncthreads();
    #pragma unroll
    for (int e = 0; e < 8; e++) {
        int idx = t + e * 256;
        float s = red[idx] + red[2048 + idx] + red[4096 + idx] + red[6144 + idx];
        part[(size_t)by * (N * D) + (size_t)i0 * D + idx] = s;
    }
}

// ---------------------------------------------------------------------------
// K5: out = cell + sum_{by=0..15} part[by]. grid 256, block 256.
// ---------------------------------------------------------------------------
__global__ __launch_bounds__(256) void reduce_kernel(
    const float* __restrict__ cell, const float* __restrict__ part,
    float* __restrict__ out)
{
    const int idx = blockIdx.x * 256 + threadIdx.x;
    float s = cell[idx];
    #pragma unroll
    for (int k = 0; k < 16; k++) s += part[(size_t)k * (N * D) + idx];
    out[idx] = s;
}

// ---------------------------------------------------------------------------
extern "C" void kernel_launch(void* const* d_in, const int* in_sizes, int n_in,
                              void* d_out, int out_size, void* d_ws, size_t ws_size,
                              hipStream_t stream) {
    const float* cell = (const float*)d_in[0];
    const float* adj  = (const float*)d_in[1];
    const float* w1   = (const float*)d_in[2];
    const float* b1   = (const float*)d_in[3];
    const float* w2   = (const float*)d_in[4];
    const float* b2   = (const float*)d_in[5];
    const float* w3   = (const float*)d_in[6];
    const float* b3   = (const float*)d_in[7];
    const float* sw   = (const float*)d_in[8];
    const float* sb   = (const float*)d_in[9];
    float* out = (float*)d_out;

    float* ws    = (float*)d_ws;
    float* m_ws  = ws;                       // 1024
    float* rs_ws = ws + 1024;                // 1024
    float* hi    = ws + 2048;                // 64K
    float* hjb   = hi + N * D;               // 64K
    float* trf   = hjb + N * D;              // 64K
    float* S     = trf + N * D;              // 1M
    float* part  = S + (size_t)N * N;        // 1M (16 x 64K)
    float* maxp  = part + (size_t)N * D * 16;// 16K
    float* sump  = maxp + N * 16;            // 16K

    symS_kernel<<<dim3(16, 16), 256, 0, stream>>>(adj, S, maxp, sump);
    stats2_kernel<<<4, 256, 0, stream>>>(maxp, sump, m_ws, rs_ws);
    precompute_kernel<<<256, 256, 0, stream>>>(cell, w1, b1, sw, sb, hi, hjb, trf);
    gate_fused_kernel<<<dim3(32, 16), 256, 0, stream>>>(S, hi, hjb, trf,
                                                        w2, b2, w3, b3,
                                                        m_ws, rs_ws, part);
    reduce_kernel<<<256, 256, 0, stream>>>(cell, part, out);
}

// Round 4
// 31.700 us; speedup vs baseline: 6.4155x; 1.1263x over previous
//
#include <hip/hip_runtime.h>
#include <hip/hip_bf16.h>

#define N 1024
#define D 64

typedef __attribute__((ext_vector_type(8))) short bf16x8;
typedef __attribute__((ext_vector_type(16))) float f32x16;

__device__ __forceinline__ short f2bf(float x) {
    __hip_bfloat16 b = __float2bfloat16(x);
    return __builtin_bit_cast(short, b);
}

// ---------------------------------------------------------------------------
// K1: hi = X@w1a^T ; hjb = X@w1b^T + b1 ; trf = X@sig_w^T + sb.
// LDS-staged weights (+1 pad -> conflict-free), i-tile 4, grid 256, block 256.
// ---------------------------------------------------------------------------
__global__ __launch_bounds__(256) void precompute_kernel(
    const float* __restrict__ cell, const float* __restrict__ w1,
    const float* __restrict__ b1, const float* __restrict__ sw,
    const float* __restrict__ sb,
    float* __restrict__ hi, float* __restrict__ hjb, float* __restrict__ trf)
{
    __shared__ float w1s[64 * 129];
    __shared__ float sws[64 * 65];
    __shared__ float xs[4 * 64];
    const int t = threadIdx.x;
    const int b = blockIdx.x;
    #pragma unroll
    for (int k = 0; k < 8; k++) {
        int f4 = t + 256 * k;
        int row = f4 >> 5, c4 = (f4 & 31) * 4;
        float4 v = *(const float4*)&w1[(size_t)row * 128 + c4];
        w1s[row * 129 + c4 + 0] = v.x;
        w1s[row * 129 + c4 + 1] = v.y;
        w1s[row * 129 + c4 + 2] = v.z;
        w1s[row * 129 + c4 + 3] = v.w;
    }
    #pragma unroll
    for (int k = 0; k < 4; k++) {
        int f4 = t + 256 * k;
        int row = f4 >> 4, c4 = (f4 & 15) * 4;
        float4 v = *(const float4*)&sw[(size_t)row * 64 + c4];
        sws[row * 65 + c4 + 0] = v.x;
        sws[row * 65 + c4 + 1] = v.y;
        sws[row * 65 + c4 + 2] = v.z;
        sws[row * 65 + c4 + 3] = v.w;
    }
    xs[t] = cell[(size_t)b * 256 + t];
    __syncthreads();
    const int wv = t >> 6, l = t & 63;
    const float* xr = &xs[wv * 64];
    float a0 = 0.0f, a1 = 0.0f, a2 = 0.0f;
    #pragma unroll 16
    for (int d = 0; d < 64; d++) {
        float x = xr[d];
        a0 = fmaf(x, w1s[l * 129 + d], a0);
        a1 = fmaf(x, w1s[l * 129 + 64 + d], a1);
        a2 = fmaf(x, sws[l * 65 + d], a2);
    }
    const int i = b * 4 + wv;
    hi[(size_t)i * D + l]  = a0;
    hjb[(size_t)i * D + l] = a1 + b1[l];
    trf[(size_t)i * D + l] = a2 + sb[l];
}

// ---------------------------------------------------------------------------
// K2: fused pairwise gate MLP + UNNORMALIZED weighted accumulation.
// sym computed on the fly from two LDS-staged A tiles (no S matrix).
// u = gate * exp(sym) (diag -> 0); es = sum_j exp(sym) (diag -> 1).
// part[by][i][d] = sum_{j in tile} u * trf ; rsp[by][i] = es partial.
// Block: 4 waves, i-tile 32, j-tile 64. grid (32,16), block 256.
// ---------------------------------------------------------------------------
__global__ __launch_bounds__(256, 3) void gate_fused_kernel(
    const float* __restrict__ A, const float* __restrict__ hi,
    const float* __restrict__ hjb, const float* __restrict__ trf,
    const float* __restrict__ w2, const float* __restrict__ b2,
    const float* __restrict__ w3, const float* __restrict__ b3,
    float* __restrict__ part, float* __restrict__ rsp)
{
    __shared__ float smem[8352];
    float* S1    = smem;           // [64 j][32 i]   A[j][i] side
    float* T2    = smem + 2048;    // [32 i][65]     A[i][j] side (padded)
    float* hjb_s = smem + 4128;    // [64 j][64 k]
    const int t   = threadIdx.x;
    const int w   = t >> 6;
    const int l   = t & 63;
    const int i0  = blockIdx.x * 32;
    const int by  = blockIdx.y;
    const int jb0 = by * 64;
    const int jbase = jb0 + w * 16;
    const int p   = l & 31;
    const int hi8 = l >> 5;
    const int i_mine = i0 + p;

    // stage hjb rows [jb0, jb0+64)
    #pragma unroll
    for (int k = 0; k < 4; k++) {
        int f4 = t + 256 * k;
        *(float4*)&hjb_s[f4 * 4] = *(const float4*)&hjb[(size_t)jb0 * D + f4 * 4];
    }
    // stage A[j][i-tile]  (64 rows x 32)
    #pragma unroll
    for (int k = 0; k < 2; k++) {
        int f4 = t + 256 * k;
        int row = f4 >> 3, c4 = (f4 & 7) * 4;
        *(float4*)&S1[row * 32 + c4] =
            *(const float4*)&A[(size_t)(jb0 + row) * N + i0 + c4];
    }
    // stage A[i-tile][j]  (32 rows x 64, pad 65)
    #pragma unroll
    for (int k = 0; k < 2; k++) {
        int f4 = t + 256 * k;
        int r = f4 >> 4, c4 = (f4 & 15) * 4;
        float4 v = *(const float4*)&A[(size_t)(i0 + r) * N + jb0 + c4];
        T2[r * 65 + c4 + 0] = v.x;
        T2[r * 65 + c4 + 1] = v.y;
        T2[r * 65 + c4 + 2] = v.z;
        T2[r * 65 + c4 + 3] = v.w;
    }

    // per-lane loop-invariant operands
    float hv[32];
    #pragma unroll
    for (int q = 0; q < 4; q++) {
        float4 v0 = *(const float4*)&hi[(size_t)i_mine * D + q * 16 + hi8 * 8];
        float4 v1 = *(const float4*)&hi[(size_t)i_mine * D + q * 16 + hi8 * 8 + 4];
        hv[q * 8 + 0] = v0.x; hv[q * 8 + 1] = v0.y;
        hv[q * 8 + 2] = v0.z; hv[q * 8 + 3] = v0.w;
        hv[q * 8 + 4] = v1.x; hv[q * 8 + 5] = v1.y;
        hv[q * 8 + 6] = v1.z; hv[q * 8 + 7] = v1.w;
    }
    bf16x8 wa[4];
    #pragma unroll
    for (int q = 0; q < 4; q++) {
        const float* wp = &w2[(size_t)p * D + q * 16 + hi8 * 8];
        #pragma unroll
        for (int e = 0; e < 8; e++) wa[q][e] = f2bf(wp[e]);
    }
    float b2r[16], w3r[16];
    #pragma unroll
    for (int r = 0; r < 16; r++) {
        int ch = (r & 3) + 8 * (r >> 2) + 4 * hi8;
        b2r[r] = b2[ch];
        w3r[r] = w3[ch];
    }
    const float b3v = b3[0];

    __syncthreads();

    bf16x8 wf = {0, 0, 0, 0, 0, 0, 0, 0};
    float es = 0.0f;
    #pragma unroll
    for (int jj = 0; jj < 16; jj++) {
        const int jl = w * 16 + jj;
        const int j  = jb0 + jl;
        bf16x8 bq[4];
        #pragma unroll
        for (int q = 0; q < 4; q++) {
            float4 h0 = *(const float4*)&hjb_s[jl * 64 + q * 16 + hi8 * 8];
            float4 h1 = *(const float4*)&hjb_s[jl * 64 + q * 16 + hi8 * 8 + 4];
            bq[q][0] = f2bf(fmaxf(hv[q * 8 + 0] + h0.x, 0.0f));
            bq[q][1] = f2bf(fmaxf(hv[q * 8 + 1] + h0.y, 0.0f));
            bq[q][2] = f2bf(fmaxf(hv[q * 8 + 2] + h0.z, 0.0f));
            bq[q][3] = f2bf(fmaxf(hv[q * 8 + 3] + h0.w, 0.0f));
            bq[q][4] = f2bf(fmaxf(hv[q * 8 + 4] + h1.x, 0.0f));
            bq[q][5] = f2bf(fmaxf(hv[q * 8 + 5] + h1.y, 0.0f));
            bq[q][6] = f2bf(fmaxf(hv[q * 8 + 6] + h1.z, 0.0f));
            bq[q][7] = f2bf(fmaxf(hv[q * 8 + 7] + h1.w, 0.0f));
        }
        f32x16 accA, accB;
        #pragma unroll
        for (int r = 0; r < 16; r++) { accA[r] = b2r[r]; accB[r] = 0.0f; }
        accA = __builtin_amdgcn_mfma_f32_32x32x16_bf16(wa[0], bq[0], accA, 0, 0, 0);
        accA = __builtin_amdgcn_mfma_f32_32x32x16_bf16(wa[1], bq[1], accA, 0, 0, 0);
        accB = __builtin_amdgcn_mfma_f32_32x32x16_bf16(wa[2], bq[2], accB, 0, 0, 0);
        accB = __builtin_amdgcn_mfma_f32_32x32x16_bf16(wa[3], bq[3], accB, 0, 0, 0);

        float gp = 0.0f;
        #pragma unroll
        for (int r = 0; r < 16; r++)
            gp = fmaf(fmaxf(accA[r] + accB[r], 0.0f), w3r[r], gp);
        gp += __shfl_xor(gp, 32);

        const bool isdiag = (i_mine == j);
        float sym  = 0.5f * (S1[jl * 32 + p] + T2[p * 65 + jl]);
        float e    = isdiag ? 1.0f : __expf(sym);   // ref: sym_ii = 0 -> exp 1
        float gate = 1.0f / (1.0f + __expf(-(gp + b3v)));
        float u    = isdiag ? 0.0f : gate * e;
        if ((jj >> 3) == hi8) es += e;
        short ub = f2bf(u);
        wf[jj & 7] = ((jj >> 3) == hi8) ? ub : wf[jj & 7];
    }
    es += __shfl_xor(es, 32);

    // post-loop: trf B-frags (k = local j), out tile = U @ trf
    bf16x8 tf0, tf1;
    #pragma unroll
    for (int e8 = 0; e8 < 8; e8++) {
        const float* tp = &trf[(size_t)(jbase + hi8 * 8 + e8) * D];
        tf0[e8] = f2bf(tp[p]);
        tf1[e8] = f2bf(tp[32 + p]);
    }
    f32x16 oA, oB;
    #pragma unroll
    for (int r = 0; r < 16; r++) { oA[r] = 0.0f; oB[r] = 0.0f; }
    oA = __builtin_amdgcn_mfma_f32_32x32x16_bf16(wf, tf0, oA, 0, 0, 0);
    oB = __builtin_amdgcn_mfma_f32_32x32x16_bf16(wf, tf1, oB, 0, 0, 0);

    __syncthreads();   // all waves done reading staged LDS
    float* red = smem;           // aliases staging region
    float* esb = smem + 8192;    // 128 floats
    #pragma unroll
    for (int r = 0; r < 16; r++) {
        int row = (r & 3) + 8 * (r >> 2) + 4 * hi8;
        red[w * 2048 + row * 64 + p]      = oA[r];
        red[w * 2048 + row * 64 + 32 + p] = oB[r];
    }
    if (hi8 == 0) esb[w * 32 + p] = es;
    __syncthreads();
    #pragma unroll
    for (int e = 0; e < 8; e++) {
        int idx = t + e * 256;
        float s = red[idx] + red[2048 + idx] + red[4096 + idx] + red[6144 + idx];
        part[(size_t)by * (N * D) + (size_t)i0 * D + idx] = s;
    }
    if (t < 32)
        rsp[by * N + i0 + t] = esb[t] + esb[32 + t] + esb[64 + t] + esb[96 + t];
}

// ---------------------------------------------------------------------------
// K3: out = cell + (sum_by part) / (sum_by rsp). grid 256, block 256.
// ---------------------------------------------------------------------------
__global__ __launch_bounds__(256) void finish_kernel(
    const float* __restrict__ cell, const float* __restrict__ part,
    const float* __restrict__ rsp, float* __restrict__ out)
{
    const int idx = blockIdx.x * 256 + threadIdx.x;
    const int i = idx >> 6;
    float rs = 0.0f;
    #pragma unroll
    for (int k = 0; k < 16; k++) rs += rsp[k * N + i];
    float acc = 0.0f;
    #pragma unroll
    for (int k = 0; k < 16; k++) acc += part[(size_t)k * (N * D) + idx];
    out[idx] = cell[idx] + acc / rs;
}

// ---------------------------------------------------------------------------
extern "C" void kernel_launch(void* const* d_in, const int* in_sizes, int n_in,
                              void* d_out, int out_size, void* d_ws, size_t ws_size,
                              hipStream_t stream) {
    const float* cell = (const float*)d_in[0];
    const float* adj  = (const float*)d_in[1];
    const float* w1   = (const float*)d_in[2];
    const float* b1   = (const float*)d_in[3];
    const float* w2   = (const float*)d_in[4];
    const float* b2   = (const float*)d_in[5];
    const float* w3   = (const float*)d_in[6];
    const float* b3   = (const float*)d_in[7];
    const float* sw   = (const float*)d_in[8];
    const float* sb   = (const float*)d_in[9];
    float* out = (float*)d_out;

    float* ws    = (float*)d_ws;
    float* hi    = ws;                        // 64K
    float* hjb   = hi + N * D;                // 64K
    float* trf   = hjb + N * D;               // 64K
    float* part  = trf + N * D;               // 1M (16 x 64K)
    float* rsp   = part + (size_t)N * D * 16; // 16K

    precompute_kernel<<<256, 256, 0, stream>>>(cell, w1, b1, sw, sb, hi, hjb, trf);
    gate_fused_kernel<<<dim3(32, 16), 256, 0, stream>>>(adj, hi, hjb, trf,
                                                        w2, b2, w3, b3,
                                                        part, rsp);
    finish_kernel<<<256, 256, 0, stream>>>(cell, part, rsp, out);
}